// Round 6
// baseline (356.289 us; speedup 1.0000x reference)
//
#include <hip/hip_runtime.h>
#include <hip/hip_cooperative_groups.h>
#include <math.h>

namespace cg = cooperative_groups;

#define NPIX 1048576
#define HH 64
#define NO 3
#define NBLK 2048
#define NTILE 65536          // NPIX / 16 pixel-tiles
#define NOUT4 786432         // NPIX*NO/4 float4s
#define K2C 2.8853900817779268f  // 2*log2(e)

typedef float f32x4 __attribute__((ext_vector_type(4)));
typedef __bf16 bf16x8 __attribute__((ext_vector_type(8)));
typedef __bf16 bf16x2 __attribute__((ext_vector_type(2)));

union BF8 { __bf16 h[8]; bf16x8 v; uint4 u4; };
union PK2 { bf16x2 h; unsigned u; };
union F4U { float f[4]; uint4 u; f32x4 v; };

#define MFMA16(a, b, c) __builtin_amdgcn_mfma_f32_16x16x32_bf16((a), (b), (c), 0, 0, 0)

// k-slot -> physical h index permutation: lane (G,q) holds C rows {16m+4G+r}
// and owns B-frag k-slots {8G+j} (Bf0) and {32+8G+j} (Bf1). Bijection:
__device__ __forceinline__ int hsel(int k) {
    const int G = (k & 31) >> 3, j = k & 7;
    return ((k >= 32) ? 32 : 0) + ((j >= 4) ? 16 : 0) + 4 * G + (j & 3);
}

// 4 tanh (pre-scaled inputs) -> 2 packed bf16 dwords; pairwise-combined rcp.
// tanh(x) = 1 - 2/(exp2(t)+1), t = 2*log2e*x (scale folded upstream).
// Overflow-safe: a*b -> inf => rcp -> 0 => i -> 0 => t -> 1 (correct saturation).
__device__ __forceinline__ void tanh4_pack(const f32x4 c, unsigned* lo, unsigned* hi) {
    const float a0 = __builtin_amdgcn_exp2f(c[0]) + 1.0f;
    const float a1 = __builtin_amdgcn_exp2f(c[1]) + 1.0f;
    const float a2 = __builtin_amdgcn_exp2f(c[2]) + 1.0f;
    const float a3 = __builtin_amdgcn_exp2f(c[3]) + 1.0f;
    const float r01 = __builtin_amdgcn_rcpf(a0 * a1);
    const float r23 = __builtin_amdgcn_rcpf(a2 * a3);
    const float t0 = fmaf(-2.0f, a1 * r01, 1.0f);
    const float t1 = fmaf(-2.0f, a0 * r01, 1.0f);
    const float t2 = fmaf(-2.0f, a3 * r23, 1.0f);
    const float t3 = fmaf(-2.0f, a2 * r23, 1.0f);
    PK2 L, H;
    L.h = bf16x2{(__bf16)t0, (__bf16)t1};
    H.h = bf16x2{(__bf16)t2, (__bf16)t3};
    *lo = L.u; *hi = H.u;
}

// ---- pre-pack, 4-wave parallel (layout per lane: 18 uint4) ----
// [0..3]=A1 (K2-scaled, bias k-aug), [4..11]=A2 (K2-scaled, k-permuted),
// [12..13]=A3 (k-permuted), [14..17]=K2*b2 C-init slice
__global__ __launch_bounds__(256) void cppn_pack(
    const float* __restrict__ W1, const float* __restrict__ b1,
    const float* __restrict__ W2, const float* __restrict__ b2,
    const float* __restrict__ W3, const float* __restrict__ b3,
    uint4* __restrict__ fr)
{
    const int t = threadIdx.x, w = t >> 6, l = t & 63, g = l >> 4, q = l & 15;
    uint4* o = fr + l * 18;

    if (w == 0) {
        #pragma unroll
        for (int m = 0; m < 4; ++m) {
            BF8 tt;
            #pragma unroll
            for (int j = 0; j < 8; ++j) {
                const int k = g * 8 + j;
                float v = 0.0f;
                if (k < 4) v = W1[k * HH + m * 16 + q];
                else if (k == 4) v = b1[m * 16 + q];
                tt.h[j] = (__bf16)(K2C * v);
            }
            o[m] = tt.u4;
        }
    } else if (w == 1 || w == 2) {
        const int s = w - 1;
        #pragma unroll
        for (int m = 0; m < 4; ++m) {
            BF8 tt;
            #pragma unroll
            for (int j = 0; j < 8; ++j)
                tt.h[j] = (__bf16)(K2C * W2[hsel(s * 32 + g * 8 + j) * HH + m * 16 + q]);
            o[4 + s * 4 + m] = tt.u4;
        }
    } else {
        #pragma unroll
        for (int s = 0; s < 2; ++s) {
            BF8 tt;
            #pragma unroll
            for (int j = 0; j < 8; ++j)
                tt.h[j] = (q < NO) ? (__bf16)W3[hsel(s * 32 + g * 8 + j) * NO + q] : (__bf16)0.0f;
            o[12 + s] = tt.u4;
        }
        #pragma unroll
        for (int m = 0; m < 4; ++m) {
            F4U tt;
            #pragma unroll
            for (int r = 0; r < 4; ++r) tt.f[r] = K2C * b2[m * 16 + g * 4 + r];
            o[14 + m] = tt.u;
        }
    }
}

// ---- phase 1 (shared by fused + fallback): grid-stride MLP, per-block min/max partials ----
__device__ __forceinline__ void main_phase(
    const float* __restrict__ x, const float* __restrict__ b3,
    const uint4* __restrict__ fr, float* __restrict__ out,
    float* __restrict__ pmin, float* __restrict__ pmax,
    float* rmin, float* rmax)
{
    const int t = threadIdx.x;
    const int w = t >> 6;
    const int l = t & 63;
    const int g = l >> 4;
    const int q = l & 15;

    const uint4* fo = fr + l * 18;
    bf16x8 A1[4], A2[2][4], A3[2];
    #pragma unroll
    for (int m = 0; m < 4; ++m) { BF8 u; u.u4 = fo[m]; A1[m] = u.v; }
    #pragma unroll
    for (int s = 0; s < 2; ++s)
        #pragma unroll
        for (int m = 0; m < 4; ++m) { BF8 u; u.u4 = fo[4 + s * 4 + m]; A2[s][m] = u.v; }
    #pragma unroll
    for (int s = 0; s < 2; ++s) { BF8 u; u.u4 = fo[12 + s]; A3[s] = u.v; }
    f32x4 Ci2[4];
    #pragma unroll
    for (int m = 0; m < 4; ++m) { F4U u; u.u = fo[14 + m]; Ci2[m] = u.v; }
    f32x4 Ci3 = {0.0f, 0.0f, 0.0f, 0.0f};
    if (g == 0) { Ci3[0] = b3[0]; Ci3[1] = b3[1]; Ci3[2] = b3[2]; }

    const f32x4 z = {0.0f, 0.0f, 0.0f, 0.0f};
    float vmin = INFINITY, vmax = -INFINITY;

    const int gs = gridDim.x * 4;            // tile stride (waves in grid)
    const int gwid = blockIdx.x * 4 + w;
    const float4* x4 = reinterpret_cast<const float4*>(x);

    float4 cur = x4[gwid * 16 + q];

    #pragma unroll 2
    for (int tile = gwid; tile < NTILE; tile += gs) {
        const int tn = (tile + gs < NTILE) ? tile + gs : tile;
        const float4 nxt = x4[tn * 16 + q];

        // B1 frag: xaug^T[k][px]; only g==0 lanes carry {x0..x3, 1}
        BF8 bx;
        bx.u4 = uint4{0, 0, 0, 0};
        if (g == 0) {
            PK2 p01, p23;
            p01.h = bf16x2{(__bf16)cur.x, (__bf16)cur.y};
            p23.h = bf16x2{(__bf16)cur.z, (__bf16)cur.w};
            bx.u4.x = p01.u;
            bx.u4.y = p23.u;
            bx.u4.z = 0x3F80u;  // 1.0bf16 bias lane (k=4)
        }

        // layer 1 (K2 pre-scaled, bias k-aug)
        f32x4 c1[4];
        #pragma unroll
        for (int m = 0; m < 4; ++m) c1[m] = MFMA16(A1[m], bx.v, z);

        unsigned pkx[4], pky[4];
        #pragma unroll
        for (int m = 0; m < 4; ++m) tanh4_pack(c1[m], &pkx[m], &pky[m]);
        BF8 Bf0, Bf1;
        Bf0.u4 = uint4{pkx[0], pky[0], pkx[1], pky[1]};
        Bf1.u4 = uint4{pkx[2], pky[2], pkx[3], pky[3]};

        // layer 2 (bias via C-init; K2 pre-scaled)
        f32x4 c2[4];
        #pragma unroll
        for (int m = 0; m < 4; ++m) {
            c2[m] = MFMA16(A2[0][m], Bf0.v, Ci2[m]);
            c2[m] = MFMA16(A2[1][m], Bf1.v, c2[m]);
        }
        #pragma unroll
        for (int m = 0; m < 4; ++m) tanh4_pack(c2[m], &pkx[m], &pky[m]);
        BF8 Bg0, Bg1;
        Bg0.u4 = uint4{pkx[0], pky[0], pkx[1], pky[1]};
        Bg1.u4 = uint4{pkx[2], pky[2], pkx[3], pky[3]};

        // layer 3 (bias via C-init)
        f32x4 c3 = MFMA16(A3[0], Bg0.v, Ci3);
        c3 = MFMA16(A3[1], Bg1.v, c3);

        if (g == 0) {
            const int pxg = tile * 16 + q;
            out[0 * NPIX + pxg] = c3[0];
            out[1 * NPIX + pxg] = c3[1];
            out[2 * NPIX + pxg] = c3[2];
            vmin = fminf(vmin, fminf(fminf(c3[0], c3[1]), c3[2]));
            vmax = fmaxf(vmax, fmaxf(fmaxf(c3[0], c3[1]), c3[2]));
        }
        cur = nxt;
    }

    #pragma unroll
    for (int off = 32; off > 0; off >>= 1) {
        vmin = fminf(vmin, __shfl_down(vmin, off));
        vmax = fmaxf(vmax, __shfl_down(vmax, off));
    }
    if (l == 0) { rmin[w] = vmin; rmax[w] = vmax; }
    __syncthreads();
    if (t == 0) {
        pmin[blockIdx.x] = fminf(fminf(rmin[0], rmin[1]), fminf(rmin[2], rmin[3]));
        pmax[blockIdx.x] = fmaxf(fmaxf(rmax[0], rmax[1]), fmaxf(rmax[2], rmax[3]));
    }
}

// ---- fused cooperative kernel: MLP -> grid.sync -> redundant reduce -> norm ----
__global__ __launch_bounds__(256, 8) void cppn_fused(
    const float* __restrict__ x, const float* __restrict__ b3,
    const uint4* __restrict__ fr, float* __restrict__ out,
    float* __restrict__ pmin, float* __restrict__ pmax)
{
    __shared__ float rmin[4], rmax[4];
    main_phase(x, b3, fr, out, pmin, pmax, rmin, rmax);

    __threadfence();
    cg::this_grid().sync();

    // every block redundantly folds the per-block partials (L2-resident)
    const int t = threadIdx.x, w = t >> 6, l = t & 63;
    float mn = INFINITY, mx = -INFINITY;
    for (int i = t; i < (int)gridDim.x; i += 256) {
        mn = fminf(mn, pmin[i]);
        mx = fmaxf(mx, pmax[i]);
    }
    #pragma unroll
    for (int off = 32; off > 0; off >>= 1) {
        mn = fminf(mn, __shfl_down(mn, off));
        mx = fmaxf(mx, __shfl_down(mx, off));
    }
    if (l == 0) { rmin[w] = mn; rmax[w] = mx; }
    __syncthreads();
    mn = fminf(fminf(rmin[0], rmin[1]), fminf(rmin[2], rmin[3]));
    mx = fmaxf(fmaxf(rmax[0], rmax[1]), fmaxf(rmax[2], rmax[3]));
    const float inv = __fdividef(1.0f, mx - mn);

    float4* o4 = reinterpret_cast<float4*>(out);
    for (int i = blockIdx.x * 256 + t; i < NOUT4; i += (int)gridDim.x * 256) {
        float4 v = o4[i];
        v.x = fminf(fmaxf((v.x - mn) * inv, 0.0f), 1.0f);
        v.y = fminf(fmaxf((v.y - mn) * inv, 0.0f), 1.0f);
        v.z = fminf(fmaxf((v.z - mn) * inv, 0.0f), 1.0f);
        v.w = fminf(fmaxf((v.w - mn) * inv, 0.0f), 1.0f);
        o4[i] = v;
    }
}

// ---- fallback (non-cooperative) path ----
__global__ __launch_bounds__(256) void cppn_main_k(
    const float* __restrict__ x, const float* __restrict__ b3,
    const uint4* __restrict__ fr, float* __restrict__ out,
    float* __restrict__ pmin, float* __restrict__ pmax)
{
    __shared__ float rmin[4], rmax[4];
    main_phase(x, b3, fr, out, pmin, pmax, rmin, rmax);
}

__global__ __launch_bounds__(256) void cppn_reduce(
    const float* __restrict__ pmin, const float* __restrict__ pmax,
    float* __restrict__ mm)
{
    __shared__ float rmin[4], rmax[4];
    const int t = threadIdx.x, w = t >> 6, l = t & 63;
    float mn = INFINITY, mx = -INFINITY;
    for (int i = t; i < NBLK; i += 256) {
        mn = fminf(mn, pmin[i]);
        mx = fmaxf(mx, pmax[i]);
    }
    #pragma unroll
    for (int off = 32; off > 0; off >>= 1) {
        mn = fminf(mn, __shfl_down(mn, off));
        mx = fmaxf(mx, __shfl_down(mx, off));
    }
    if (l == 0) { rmin[w] = mn; rmax[w] = mx; }
    __syncthreads();
    if (t == 0) {
        mm[0] = fminf(fminf(rmin[0], rmin[1]), fminf(rmin[2], rmin[3]));
        mm[1] = fmaxf(fmaxf(rmax[0], rmax[1]), fmaxf(rmax[2], rmax[3]));
    }
}

__global__ __launch_bounds__(256) void cppn_norm(float4* __restrict__ out,
                                                 const float* __restrict__ mm)
{
    const float mn = mm[0];
    const float mx = mm[1];
    const float inv = __fdividef(1.0f, mx - mn);
    const int i = blockIdx.x * 256 + threadIdx.x;
    float4 v = out[i];
    v.x = fminf(fmaxf((v.x - mn) * inv, 0.0f), 1.0f);
    v.y = fminf(fmaxf((v.y - mn) * inv, 0.0f), 1.0f);
    v.z = fminf(fmaxf((v.z - mn) * inv, 0.0f), 1.0f);
    v.w = fminf(fmaxf((v.w - mn) * inv, 0.0f), 1.0f);
    out[i] = v;
}

extern "C" void kernel_launch(void* const* d_in, const int* in_sizes, int n_in,
                              void* d_out, int out_size, void* d_ws, size_t ws_size,
                              hipStream_t stream) {
    const float* x  = (const float*)d_in[0];
    const float* W1 = (const float*)d_in[1];
    const float* b1 = (const float*)d_in[2];
    const float* W2 = (const float*)d_in[3];
    const float* b2 = (const float*)d_in[4];
    const float* W3 = (const float*)d_in[5];
    const float* b3 = (const float*)d_in[6];
    float* out = (float*)d_out;

    float* mm   = (float*)d_ws;
    float* pmin = (float*)((char*)d_ws + 1024);
    float* pmax = (float*)((char*)d_ws + 1024 + 8192);
    uint4* fr   = (uint4*)((char*)d_ws + 32768);

    cppn_pack<<<1, 256, 0, stream>>>(W1, b1, W2, b2, W3, b3, fr);

    // cooperative fused path (host-side queries are capture-safe; deterministic)
    int dev = 0; hipGetDevice(&dev);
    int nbpm = 0, ncu = 0;
    hipOccupancyMaxActiveBlocksPerMultiprocessor(&nbpm, (const void*)cppn_fused, 256, 0);
    hipDeviceGetAttribute(&ncu, hipDeviceAttributeMultiprocessorCount, dev);
    long grid = (long)nbpm * (long)ncu;
    if (grid > NBLK) grid = NBLK;

    hipError_t e = hipErrorUnknown;
    if (grid >= 64) {
        const float* xa = x; const float* b3a = b3; const uint4* fra = fr;
        float* outa = out; float* pmina = pmin; float* pmaxa = pmax;
        void* args[] = {&xa, &b3a, &fra, &outa, &pmina, &pmaxa};
        e = hipLaunchCooperativeKernel((const void*)cppn_fused, dim3((int)grid), dim3(256),
                                       args, 0, stream);
    }
    if (e != hipSuccess) {
        // fallback: 3-kernel pipeline (same math)
        cppn_main_k<<<NBLK, 256, 0, stream>>>(x, b3, fr, out, pmin, pmax);
        cppn_reduce<<<1, 256, 0, stream>>>(pmin, pmax, mm);
        cppn_norm<<<NOUT4 / 256, 256, 0, stream>>>((float4*)out, mm);
    }
}

// Round 7
// 52.968 us; speedup vs baseline: 6.7265x; 6.7265x over previous
//
#include <hip/hip_runtime.h>
#include <math.h>

#define NPIX 1048576
#define HH 64
#define NO 3
#define NBLK 2048
#define ITER 8     // NBLK * 4 waves * ITER * 16 px = 1048576
#define NOUT4 786432             // NPIX*NO/4 float4s
#define K2C 2.8853900817779268f  // 2*log2(e)

typedef float f32x4 __attribute__((ext_vector_type(4)));
typedef __bf16 bf16x8 __attribute__((ext_vector_type(8)));
typedef __bf16 bf16x2 __attribute__((ext_vector_type(2)));

union BF8 { __bf16 h[8]; bf16x8 v; uint4 u4; };
union PK2 { bf16x2 h; unsigned u; };
union F4U { float f[4]; uint4 u; f32x4 v; };

#define MFMA16(a, b, c) __builtin_amdgcn_mfma_f32_16x16x32_bf16((a), (b), (c), 0, 0, 0)

// k-slot -> physical h index permutation: lane (G,q) holds C rows {16m+4G+r}
// and owns B-frag k-slots {8G+j} (Bf0) and {32+8G+j} (Bf1). Bijection:
__device__ __forceinline__ int hsel(int k) {
    const int G = (k & 31) >> 3, j = k & 7;
    return ((k >= 32) ? 32 : 0) + ((j >= 4) ? 16 : 0) + 4 * G + (j & 3);
}

// 4 tanh (inputs pre-scaled by 2*log2e, bias folded) -> 2 packed bf16 dwords.
// tanh = 1 - 2/(exp2(t)+1); pairwise-combined rcp: 1/a,1/b from rcp(a*b).
// Overflow-safe: a*b -> inf => rcp -> 0 => fma(-2,0,1) = 1 (correct saturation).
__device__ __forceinline__ void tanh4_pack(const f32x4 c, unsigned* lo, unsigned* hi) {
    const float a0 = __builtin_amdgcn_exp2f(c[0]) + 1.0f;
    const float a1 = __builtin_amdgcn_exp2f(c[1]) + 1.0f;
    const float a2 = __builtin_amdgcn_exp2f(c[2]) + 1.0f;
    const float a3 = __builtin_amdgcn_exp2f(c[3]) + 1.0f;
    const float r01 = __builtin_amdgcn_rcpf(a0 * a1);
    const float r23 = __builtin_amdgcn_rcpf(a2 * a3);
    const float t0 = fmaf(-2.0f, a1 * r01, 1.0f);
    const float t1 = fmaf(-2.0f, a0 * r01, 1.0f);
    const float t2 = fmaf(-2.0f, a3 * r23, 1.0f);
    const float t3 = fmaf(-2.0f, a2 * r23, 1.0f);
    PK2 L, H;
    L.h = bf16x2{(__bf16)t0, (__bf16)t1};
    H.h = bf16x2{(__bf16)t2, (__bf16)t3};
    *lo = L.u; *hi = H.u;
}

// ---- pre-pack, 4-wave parallel (layout per lane: 18 uint4) ----
// [0..3]=A1 (K2-scaled, bias k-aug), [4..11]=A2 (K2-scaled, k-permuted),
// [12..13]=A3 (k-permuted), [14..17]=K2*b2 C-init slice
__global__ __launch_bounds__(256) void cppn_pack(
    const float* __restrict__ W1, const float* __restrict__ b1,
    const float* __restrict__ W2, const float* __restrict__ b2,
    const float* __restrict__ W3, const float* __restrict__ b3,
    uint4* __restrict__ fr)
{
    const int t = threadIdx.x, w = t >> 6, l = t & 63, g = l >> 4, q = l & 15;
    uint4* o = fr + l * 18;

    if (w == 0) {
        #pragma unroll
        for (int m = 0; m < 4; ++m) {
            BF8 tt;
            #pragma unroll
            for (int j = 0; j < 8; ++j) {
                const int k = g * 8 + j;
                float v = 0.0f;
                if (k < 4) v = W1[k * HH + m * 16 + q];
                else if (k == 4) v = b1[m * 16 + q];
                tt.h[j] = (__bf16)(K2C * v);
            }
            o[m] = tt.u4;
        }
    } else if (w == 1 || w == 2) {
        const int s = w - 1;
        #pragma unroll
        for (int m = 0; m < 4; ++m) {
            BF8 tt;
            #pragma unroll
            for (int j = 0; j < 8; ++j)
                tt.h[j] = (__bf16)(K2C * W2[hsel(s * 32 + g * 8 + j) * HH + m * 16 + q]);
            o[4 + s * 4 + m] = tt.u4;
        }
    } else {
        #pragma unroll
        for (int s = 0; s < 2; ++s) {
            BF8 tt;
            #pragma unroll
            for (int j = 0; j < 8; ++j)
                tt.h[j] = (q < NO) ? (__bf16)W3[hsel(s * 32 + g * 8 + j) * NO + q] : (__bf16)0.0f;
            o[12 + s] = tt.u4;
        }
        #pragma unroll
        for (int m = 0; m < 4; ++m) {
            F4U tt;
            #pragma unroll
            for (int r = 0; r < 4; ++r) tt.f[r] = K2C * b2[m * 16 + g * 4 + r];
            o[14 + m] = tt.u;
        }
    }
}

__global__ __launch_bounds__(256) void cppn_main(
    const float* __restrict__ x,
    const float* __restrict__ b3,
    const uint4* __restrict__ fr,
    float* __restrict__ out,
    float* __restrict__ pmin, float* __restrict__ pmax)
{
    __shared__ float rmin[4], rmax[4];

    const int t = threadIdx.x;
    const int w = t >> 6;
    const int l = t & 63;
    const int g = l >> 4;
    const int q = l & 15;

    // ---- load prebuilt fragments (18 dwordx4, L2-hit) ----
    const uint4* fo = fr + l * 18;
    bf16x8 A1[4], A2[2][4], A3[2];
    #pragma unroll
    for (int m = 0; m < 4; ++m) { BF8 u; u.u4 = fo[m]; A1[m] = u.v; }
    #pragma unroll
    for (int s = 0; s < 2; ++s)
        #pragma unroll
        for (int m = 0; m < 4; ++m) { BF8 u; u.u4 = fo[4 + s * 4 + m]; A2[s][m] = u.v; }
    #pragma unroll
    for (int s = 0; s < 2; ++s) { BF8 u; u.u4 = fo[12 + s]; A3[s] = u.v; }
    f32x4 Ci2[4];
    #pragma unroll
    for (int m = 0; m < 4; ++m) { F4U u; u.u = fo[14 + m]; Ci2[m] = u.v; }
    const float b30 = b3[0], b31 = b3[1], b32 = b3[2];

    const f32x4 z = {0.0f, 0.0f, 0.0f, 0.0f};
    float vmin = INFINITY, vmax = -INFINITY;

    const int pbase = ((blockIdx.x * 4 + w) * ITER) * 16 + q;  // pixel index, it steps +16
    const float4* x4 = reinterpret_cast<const float4*>(x);

    float4 cur = x4[pbase];

    #pragma unroll 2
    for (int it = 0; it < ITER; ++it) {
        // prefetch next iteration's x before the long compute body
        const int itn = (it + 1 < ITER) ? it + 1 : it;
        const float4 nxt = x4[pbase + itn * 16];

        // B1 frag: xaug^T[k][px]; only g==0 lanes carry {x0..x3, 1}
        BF8 bx;
        bx.u4 = uint4{0, 0, 0, 0};
        if (g == 0) {
            PK2 p01, p23;
            p01.h = bf16x2{(__bf16)cur.x, (__bf16)cur.y};
            p23.h = bf16x2{(__bf16)cur.z, (__bf16)cur.w};
            bx.u4.x = p01.u;
            bx.u4.y = p23.u;
            bx.u4.z = 0x3F80u;  // {1.0bf16, 0} bias lane k=4
        }

        // ---- layer 1 (A1 pre-scaled by K2, bias k-augmented) ----
        f32x4 c1[4];
        #pragma unroll
        for (int m = 0; m < 4; ++m) c1[m] = MFMA16(A1[m], bx.v, z);

        unsigned pkx[4], pky[4];
        #pragma unroll
        for (int m = 0; m < 4; ++m) tanh4_pack(c1[m], &pkx[m], &pky[m]);
        BF8 Bf0, Bf1;
        Bf0.u4 = uint4{pkx[0], pky[0], pkx[1], pky[1]};
        Bf1.u4 = uint4{pkx[2], pky[2], pkx[3], pky[3]};

        // ---- layer 2 (bias via C-init; K2 pre-scaled) ----
        f32x4 c2[4];
        #pragma unroll
        for (int m = 0; m < 4; ++m) {
            c2[m] = MFMA16(A2[0][m], Bf0.v, Ci2[m]);
            c2[m] = MFMA16(A2[1][m], Bf1.v, c2[m]);
        }
        #pragma unroll
        for (int m = 0; m < 4; ++m) tanh4_pack(c2[m], &pkx[m], &pky[m]);
        BF8 Bg0, Bg1;
        Bg0.u4 = uint4{pkx[0], pky[0], pkx[1], pky[1]};
        Bg1.u4 = uint4{pkx[2], pky[2], pkx[3], pky[3]};

        // ---- layer 3 ----
        f32x4 c3 = MFMA16(A3[0], Bg0.v, z);
        c3 = MFMA16(A3[1], Bg1.v, c3);

        if (g == 0) {
            const int pxg = pbase + it * 16;
            const float o0 = c3[0] + b30;
            const float o1 = c3[1] + b31;
            const float o2 = c3[2] + b32;
            out[0 * NPIX + pxg] = o0;
            out[1 * NPIX + pxg] = o1;
            out[2 * NPIX + pxg] = o2;
            vmin = fminf(vmin, fminf(fminf(o0, o1), o2));
            vmax = fmaxf(vmax, fmaxf(fmaxf(o0, o1), o2));
        }
        cur = nxt;
    }

    // per-block min/max -> partials (no global atomics)
    #pragma unroll
    for (int off = 32; off > 0; off >>= 1) {
        vmin = fminf(vmin, __shfl_down(vmin, off));
        vmax = fmaxf(vmax, __shfl_down(vmax, off));
    }
    if (l == 0) { rmin[w] = vmin; rmax[w] = vmax; }
    __syncthreads();
    if (t == 0) {
        pmin[blockIdx.x] = fminf(fminf(rmin[0], rmin[1]), fminf(rmin[2], rmin[3]));
        pmax[blockIdx.x] = fmaxf(fmaxf(rmax[0], rmax[1]), fmaxf(rmax[2], rmax[3]));
    }
}

// fused reduce+norm: each block redundantly folds the 2048 partials (L2-hit),
// then normalizes its own float4 slice. Exact (min/max order-independent).
__global__ __launch_bounds__(256) void cppn_normred(
    float4* __restrict__ out,
    const float* __restrict__ pmin, const float* __restrict__ pmax)
{
    __shared__ float rmin[4], rmax[4];
    const int t = threadIdx.x, w = t >> 6, l = t & 63;
    float mn = INFINITY, mx = -INFINITY;
    #pragma unroll
    for (int i = 0; i < NBLK / 256; ++i) {
        mn = fminf(mn, pmin[i * 256 + t]);
        mx = fmaxf(mx, pmax[i * 256 + t]);
    }
    #pragma unroll
    for (int off = 32; off > 0; off >>= 1) {
        mn = fminf(mn, __shfl_down(mn, off));
        mx = fmaxf(mx, __shfl_down(mx, off));
    }
    if (l == 0) { rmin[w] = mn; rmax[w] = mx; }
    __syncthreads();
    mn = fminf(fminf(rmin[0], rmin[1]), fminf(rmin[2], rmin[3]));
    mx = fmaxf(fmaxf(rmax[0], rmax[1]), fmaxf(rmax[2], rmax[3]));
    const float inv = __fdividef(1.0f, mx - mn);

    const int i = blockIdx.x * 256 + t;
    float4 v = out[i];
    v.x = fminf(fmaxf((v.x - mn) * inv, 0.0f), 1.0f);
    v.y = fminf(fmaxf((v.y - mn) * inv, 0.0f), 1.0f);
    v.z = fminf(fmaxf((v.z - mn) * inv, 0.0f), 1.0f);
    v.w = fminf(fmaxf((v.w - mn) * inv, 0.0f), 1.0f);
    out[i] = v;
}

extern "C" void kernel_launch(void* const* d_in, const int* in_sizes, int n_in,
                              void* d_out, int out_size, void* d_ws, size_t ws_size,
                              hipStream_t stream) {
    const float* x  = (const float*)d_in[0];
    const float* W1 = (const float*)d_in[1];
    const float* b1 = (const float*)d_in[2];
    const float* W2 = (const float*)d_in[3];
    const float* b2 = (const float*)d_in[4];
    const float* W3 = (const float*)d_in[5];
    const float* b3 = (const float*)d_in[6];
    float* out = (float*)d_out;

    float* pmin = (float*)((char*)d_ws + 1024);          // 2048 floats
    float* pmax = (float*)((char*)d_ws + 1024 + 8192);   // 2048 floats
    uint4* fr   = (uint4*)((char*)d_ws + 32768);         // 64 lanes * 18 uint4 = 18 KB

    cppn_pack<<<1, 256, 0, stream>>>(W1, b1, W2, b2, W3, b3, fr);
    cppn_main<<<NBLK, 256, 0, stream>>>(x, b3, fr, out, pmin, pmax);
    cppn_normred<<<NOUT4 / 256, 256, 0, stream>>>((float4*)out, pmin, pmax);
}